// Round 4
// baseline (619.191 us; speedup 1.0000x reference)
//
#include <hip/hip_runtime.h>

// GCN: out = spmm(A, relu(spmm(A, x@W1)+b1) @ W2) + b2
// N=100000, E=1600000, F_IN=256, H1=128, H2=64. f32 inputs; edge_index INT32.
// Two-tier: Tier A (CSR, all-f32) when ws_size suffices; Tier C (COO atomics,
// bf16 intermediates, h staged inside d_out) otherwise.
// All edge-index consumers clamp to [0,N) so a bad index can NEVER memory-fault
// (R1's int64 misread wedged the container; never again).

constexpr int F_IN = 256, H1 = 128, H2 = 64;

__device__ inline float bf2f(unsigned short u) { return __uint_as_float((unsigned)u << 16); }
__device__ inline unsigned short f2bf(float f) {
    unsigned u = __float_as_uint(f);
    u += 0x7fff + ((u >> 16) & 1);   // round-to-nearest-even
    return (unsigned short)(u >> 16);
}

// ---------------- generic zero ----------------
__global__ __launch_bounds__(256) void k_zero32(unsigned int* __restrict__ p, long n) {
    long i = (long)blockIdx.x * 256 + threadIdx.x;
    if (i < n) p[i] = 0u;
}

// ---------------- CSR build (Tier A) ----------------
__global__ __launch_bounds__(256) void k_hist(const int* __restrict__ ei, int E, int N,
                                              int* __restrict__ cnt) {
    int e = blockIdx.x * 256 + threadIdx.x;
    if (e < E) {
        unsigned r = (unsigned)ei[e];
        if (r < (unsigned)N) atomicAdd(&cnt[r], 1);
    }
}

__global__ __launch_bounds__(512) void k_scan1(const int* __restrict__ cnt, int n,
                                               int* __restrict__ excl, int* __restrict__ bsum) {
    __shared__ int s[512];
    int tid = threadIdx.x;
    int i = blockIdx.x * 512 + tid;
    int v = (i < n) ? cnt[i] : 0;
    s[tid] = v;
    __syncthreads();
    for (int off = 1; off < 512; off <<= 1) {
        int t = (tid >= off) ? s[tid - off] : 0;
        __syncthreads();
        s[tid] += t;
        __syncthreads();
    }
    if (i < n) excl[i] = s[tid] - v;
    if (tid == 511) bsum[blockIdx.x] = s[511];
}

__global__ __launch_bounds__(256) void k_scan2(int* __restrict__ bsum, int nb) {
    __shared__ int s[256];
    int tid = threadIdx.x;
    int v = (tid < nb) ? bsum[tid] : 0;
    s[tid] = v;
    __syncthreads();
    for (int off = 1; off < 256; off <<= 1) {
        int t = (tid >= off) ? s[tid - off] : 0;
        __syncthreads();
        s[tid] += t;
        __syncthreads();
    }
    if (tid < nb) bsum[tid] = s[tid] - v;
}

__global__ __launch_bounds__(256) void k_scan3(int* __restrict__ row_ptr, int* __restrict__ cursor,
                                               const int* __restrict__ bsum, int n, int E) {
    int i = blockIdx.x * 256 + threadIdx.x;
    if (i < n) {
        int v = row_ptr[i] + bsum[i >> 9];
        row_ptr[i] = v;
        cursor[i] = v;
    }
    if (i == 0) row_ptr[n] = E;
}

__global__ __launch_bounds__(256) void k_scatter(const int* __restrict__ ei,
                                                 const float* __restrict__ ew, int E, int N,
                                                 int* __restrict__ cursor,
                                                 int* __restrict__ col_s, float* __restrict__ w_s) {
    int e = blockIdx.x * 256 + threadIdx.x;
    if (e < E) {
        unsigned r = (unsigned)ei[e];
        unsigned c = (unsigned)ei[E + e];
        if (r < (unsigned)N && c < (unsigned)N) {
            int p = atomicAdd(&cursor[r], 1);
            if ((unsigned)p < (unsigned)E) {  // belt-and-braces
                col_s[p] = (int)c;
                w_s[p] = ew[e];
            }
        }
    }
}

// ---------------- tiled GEMM: C[M][NC] = A[M][K] @ B[K][NC] ----------------
// A may be bf16 (INBF), C may be bf16 (OUTBF); B (weights) always f32.

template <int NC, int K, bool INBF, bool OUTBF>
__global__ __launch_bounds__(256) void k_gemm(const void* __restrict__ A_,
                                              const float* __restrict__ B,
                                              void* __restrict__ C_, int M) {
    constexpr int TM = 64, KC = 32;
    constexpr int TX = NC / 4;
    constexpr int TY = 256 / TX;
    constexpr int RPT = TM / TY;
    __shared__ float xs[TM][KC];
    __shared__ float bs[KC][NC];
    const int t = threadIdx.x;
    const int tx = t % TX, ty = t / TX;
    const long row0 = (long)blockIdx.x * TM;

    float4 acc[RPT];
#pragma unroll
    for (int i = 0; i < RPT; ++i) acc[i] = make_float4(0.f, 0.f, 0.f, 0.f);

    for (int kc = 0; kc < K; kc += KC) {
#pragma unroll
        for (int j = 0; j < (TM * KC) / 1024; ++j) {
            int idx4 = t + j * 256;
            int r = idx4 / (KC / 4);
            int kq = idx4 % (KC / 4);
            long gr = row0 + r;
            float4 v = make_float4(0.f, 0.f, 0.f, 0.f);
            if (gr < M) {
                if (INBF) {
                    const unsigned short* A = (const unsigned short*)A_;
                    ushort4 u = *(const ushort4*)&A[gr * K + kc + kq * 4];
                    v = make_float4(bf2f(u.x), bf2f(u.y), bf2f(u.z), bf2f(u.w));
                } else {
                    v = *(const float4*)&((const float*)A_)[gr * K + kc + kq * 4];
                }
            }
            *(float4*)&xs[r][kq * 4] = v;
        }
#pragma unroll
        for (int j = 0; j < (KC * NC) / 1024; ++j) {
            int idx4 = t + j * 256;
            int r = idx4 / (NC / 4);
            int cq = idx4 % (NC / 4);
            *(float4*)&bs[r][cq * 4] = *(const float4*)&B[(long)(kc + r) * NC + cq * 4];
        }
        __syncthreads();
#pragma unroll
        for (int kk = 0; kk < KC; ++kk) {
            float4 b = *(const float4*)&bs[kk][tx * 4];
#pragma unroll
            for (int i = 0; i < RPT; ++i) {
                float a = xs[ty + i * TY][kk];
                acc[i].x += a * b.x;
                acc[i].y += a * b.y;
                acc[i].z += a * b.z;
                acc[i].w += a * b.w;
            }
        }
        __syncthreads();
    }
#pragma unroll
    for (int i = 0; i < RPT; ++i) {
        long gr = row0 + ty + i * TY;
        if (gr < M) {
            if (OUTBF) {
                ushort4 o;
                o.x = f2bf(acc[i].x); o.y = f2bf(acc[i].y);
                o.z = f2bf(acc[i].z); o.w = f2bf(acc[i].w);
                *(ushort4*)&((unsigned short*)C_)[gr * NC + tx * 4] = o;
            } else {
                *(float4*)&((float*)C_)[gr * NC + tx * 4] = acc[i];
            }
        }
    }
}

// ---------------- CSR SPMM (Tier A): one wave per row ----------------
template <int H, bool RELU>
__global__ __launch_bounds__(256) void k_spmm(const int* __restrict__ row_ptr,
                                              const int* __restrict__ col_s,
                                              const float* __restrict__ w_s,
                                              const float* __restrict__ sup,
                                              const float* __restrict__ bias,
                                              float* __restrict__ out, int n) {
    int wid = (blockIdx.x * 256 + threadIdx.x) >> 6;
    int lane = threadIdx.x & 63;
    if (wid >= n) return;
    int s = row_ptr[wid], e = row_ptr[wid + 1];
    if (H == 128) {
        float2 acc = make_float2(0.f, 0.f);
        for (int i = s; i < e; ++i) {
            int c = col_s[i];
            float w = w_s[i];
            float2 v = *(const float2*)&sup[(long)c * H + lane * 2];
            acc.x += w * v.x;
            acc.y += w * v.y;
        }
        float2 b = *(const float2*)&bias[lane * 2];
        float o0 = acc.x + b.x, o1 = acc.y + b.y;
        if (RELU) { o0 = fmaxf(o0, 0.f); o1 = fmaxf(o1, 0.f); }
        *(float2*)&out[(long)wid * H + lane * 2] = make_float2(o0, o1);
    } else {
        float acc = 0.f;
        for (int i = s; i < e; ++i) acc += w_s[i] * sup[(long)col_s[i] * H + lane];
        float o = acc + bias[lane];
        if (RELU) o = fmaxf(o, 0.f);
        out[(long)wid * H + lane] = o;
    }
}

// ---------------- Tier C: COO atomic SPMM ----------------

__device__ inline void atomic_add_bf16x2(unsigned int* addr, float a0, float a1) {
    unsigned int old = __atomic_load_n(addr, __ATOMIC_RELAXED), assumed;
    do {
        assumed = old;
        float f0 = bf2f((unsigned short)(assumed & 0xffffu));
        float f1 = bf2f((unsigned short)(assumed >> 16));
        unsigned int nv = (unsigned)f2bf(f0 + a0) | ((unsigned)f2bf(f1 + a1) << 16);
        old = atomicCAS(addr, assumed, nv);
    } while (old != assumed);
}

__global__ __launch_bounds__(256) void k_spmm1_atomic(const int* __restrict__ ei,
                                                      const float* __restrict__ ew, int E, int N,
                                                      const unsigned short* __restrict__ sup,
                                                      unsigned int* __restrict__ h) {
    int gw = (blockIdx.x * 256 + threadIdx.x) >> 6;
    int lane = threadIdx.x & 63;
    if (gw >= E) return;
    unsigned r = (unsigned)ei[gw];
    unsigned c = (unsigned)ei[E + gw];
    if (r >= (unsigned)N || c >= (unsigned)N) return;
    float w = ew[gw];
    ushort2 s = *(const ushort2*)&sup[(long)c * H1 + lane * 2];
    atomic_add_bf16x2(&h[(long)r * 64 + lane], w * bf2f(s.x), w * bf2f(s.y));
}

__global__ __launch_bounds__(256) void k_bias_relu(unsigned int* __restrict__ h,
                                                   const float* __restrict__ b1, long n) {
    long i = (long)blockIdx.x * 256 + threadIdx.x;
    if (i >= n) return;
    int j = (int)(i & 63);
    unsigned int v = h[i];
    float f0 = fmaxf(bf2f((unsigned short)(v & 0xffffu)) + b1[2 * j], 0.f);
    float f1 = fmaxf(bf2f((unsigned short)(v >> 16)) + b1[2 * j + 1], 0.f);
    h[i] = (unsigned)f2bf(f0) | ((unsigned)f2bf(f1) << 16);
}

__global__ __launch_bounds__(256) void k_init_out(float* __restrict__ out,
                                                  const float* __restrict__ b2, long n) {
    long i = (long)blockIdx.x * 256 + threadIdx.x;
    if (i < n) out[i] = b2[i & 63];
}

__global__ __launch_bounds__(256) void k_spmm2_atomic(const int* __restrict__ ei,
                                                      const float* __restrict__ ew, int E, int N,
                                                      const float* __restrict__ sup2,
                                                      float* __restrict__ out) {
    int gw = (blockIdx.x * 256 + threadIdx.x) >> 6;
    int lane = threadIdx.x & 63;
    if (gw >= E) return;
    unsigned r = (unsigned)ei[gw];
    unsigned c = (unsigned)ei[E + gw];
    if (r >= (unsigned)N || c >= (unsigned)N) return;
    float w = ew[gw];
    atomicAdd(&out[(long)r * H2 + lane], w * sup2[(long)c * H2 + lane]);
}

// ---------------- launch ----------------

extern "C" void kernel_launch(void* const* d_in, const int* in_sizes, int n_in,
                              void* d_out, int out_size, void* d_ws, size_t ws_size,
                              hipStream_t stream) {
    (void)n_in; (void)out_size;
    const float* x = (const float*)d_in[0];
    const int* ei = (const int*)d_in[1];      // int32 (harness converts integer inputs)
    const float* ew = (const float*)d_in[2];
    const float* W1 = (const float*)d_in[3];
    const float* b1 = (const float*)d_in[4];
    const float* W2 = (const float*)d_in[5];
    const float* b2 = (const float*)d_in[6];
    float* out = (float*)d_out;

    const int E = in_sizes[2];
    const int N = in_sizes[0] / F_IN;  // 100000

    const int gE = (E + 255) / 256;
    const int gEw = (E + 3) / 4;
    const int gM = (N + 63) / 64;
    const int nb = (N + 511) / 512;

    // Tier A workspace layout (256B-aligned chunks)
    size_t off = 0;
    auto take = [&off](size_t bytes) { size_t p = off; off = (off + bytes + 255) & ~(size_t)255; return p; };
    size_t o_support = take((size_t)N * H1 * 4);
    size_t o_h       = take((size_t)N * H1 * 4);
    size_t o_rowptr  = take(((size_t)N + 1) * 4);
    size_t o_cursor  = take((size_t)N * 4);
    size_t o_bsum    = take(1024 * 4);
    size_t o_cols    = take((size_t)E * 4);
    size_t o_ws_w    = take((size_t)E * 4);
    size_t needA = off;

    char* wsb = (char*)d_ws;

    if (ws_size >= needA) {
        // ---- Tier A: CSR + all-f32 ----
        float* support = (float*)(wsb + o_support);
        float* h       = (float*)(wsb + o_h);
        int* row_ptr   = (int*)(wsb + o_rowptr);
        int* cursor    = (int*)(wsb + o_cursor);
        int* bsum      = (int*)(wsb + o_bsum);
        int* col_s     = (int*)(wsb + o_cols);
        float* w_s     = (float*)(wsb + o_ws_w);

        k_zero32<<<(N + 255) / 256, 256, 0, stream>>>((unsigned int*)cursor, N);
        k_hist<<<gE, 256, 0, stream>>>(ei, E, N, cursor);
        k_scan1<<<nb, 512, 0, stream>>>(cursor, N, row_ptr, bsum);
        k_scan2<<<1, 256, 0, stream>>>(bsum, nb);
        k_scan3<<<(N + 255) / 256, 256, 0, stream>>>(row_ptr, cursor, bsum, N, E);
        k_scatter<<<gE, 256, 0, stream>>>(ei, ew, E, N, cursor, col_s, w_s);

        k_gemm<H1, F_IN, false, false><<<gM, 256, 0, stream>>>(x, W1, support, N);
        k_spmm<H1, true><<<(N + 3) / 4, 256, 0, stream>>>(row_ptr, col_s, w_s, support, b1, h, N);
        k_gemm<H2, H1, false, false><<<gM, 256, 0, stream>>>(h, W2, support, N);
        k_spmm<H2, false><<<(N + 3) / 4, 256, 0, stream>>>(row_ptr, col_s, w_s, support, b2, out, N);
    } else {
        // ---- Tier C: COO atomics; ws holds support (bf16 / f32-64col aliased);
        //      h lives inside d_out as packed bf16 ----
        unsigned short* sup1 = (unsigned short*)d_ws;    // N*H1 bf16 = 25.6MB
        float* sup2 = (float*)d_ws;                      // N*H2 f32 = 25.6MB (aliases sup1)
        unsigned int* h = (unsigned int*)d_out;          // N*64 words (bf16 pairs)

        k_gemm<H1, F_IN, false, true><<<gM, 256, 0, stream>>>(x, W1, sup1, N);
        k_zero32<<<(N * 64 + 255) / 256, 256, 0, stream>>>(h, (long)N * 64);
        k_spmm1_atomic<<<gEw, 256, 0, stream>>>(ei, ew, E, N, sup1, h);
        k_bias_relu<<<(N * 64 + 255) / 256, 256, 0, stream>>>(h, b1, (long)N * 64);
        k_gemm<H2, H1, true, false><<<gM, 256, 0, stream>>>(h, W2, sup2, N);
        k_init_out<<<(N * 64 + 255) / 256, 256, 0, stream>>>(out, b2, (long)N * 64);
        k_spmm2_atomic<<<gEw, 256, 0, stream>>>(ei, ew, E, N, sup2, out);
    }
}

// Round 5
// 383.826 us; speedup vs baseline: 1.6132x; 1.6132x over previous
//
#include <hip/hip_runtime.h>

// GCN: out = spmm(A, relu(spmm(A, x@W1)+b1) @ W2) + b2
// N=100000, E=1600000, F_IN=256, H1=128, H2=64. f32 inputs; edge_index int32.
// R4 plan: CSR build (as R3, cw packed int2) + bf16 MFMA GEMMs (pre-transposed
// bf16 weights, XOR-swizzled LDS) + bf16 supports with unroll-4 gather SPMM.
// Edge-index consumers clamp to [0,N): a bad index degrades accuracy, never faults.

constexpr int F_IN = 256, H1 = 128, H2 = 64;

typedef __attribute__((ext_vector_type(8))) short bf16x8;
typedef __attribute__((ext_vector_type(4))) float f32x4;

__device__ inline float bf2f(unsigned short u) { return __uint_as_float((unsigned)u << 16); }
__device__ inline unsigned short f2bf(float f) {
    unsigned u = __float_as_uint(f);
    u += 0x7fff + ((u >> 16) & 1);   // round-to-nearest-even
    return (unsigned short)(u >> 16);
}

// ---------------- generic zero ----------------
__global__ __launch_bounds__(256) void k_zero32(unsigned int* __restrict__ p, long n) {
    long i = (long)blockIdx.x * 256 + threadIdx.x;
    if (i < n) p[i] = 0u;
}

// ---------------- CSR build ----------------
__global__ __launch_bounds__(256) void k_hist(const int* __restrict__ ei, int E, int N,
                                              int* __restrict__ cnt) {
    int e = blockIdx.x * 256 + threadIdx.x;
    if (e < E) {
        unsigned r = (unsigned)ei[e];
        if (r < (unsigned)N) atomicAdd(&cnt[r], 1);
    }
}

__global__ __launch_bounds__(512) void k_scan1(const int* __restrict__ cnt, int n,
                                               int* __restrict__ excl, int* __restrict__ bsum) {
    __shared__ int s[512];
    int tid = threadIdx.x;
    int i = blockIdx.x * 512 + tid;
    int v = (i < n) ? cnt[i] : 0;
    s[tid] = v;
    __syncthreads();
    for (int off = 1; off < 512; off <<= 1) {
        int t = (tid >= off) ? s[tid - off] : 0;
        __syncthreads();
        s[tid] += t;
        __syncthreads();
    }
    if (i < n) excl[i] = s[tid] - v;
    if (tid == 511) bsum[blockIdx.x] = s[511];
}

__global__ __launch_bounds__(256) void k_scan2(int* __restrict__ bsum, int nb) {
    __shared__ int s[256];
    int tid = threadIdx.x;
    int v = (tid < nb) ? bsum[tid] : 0;
    s[tid] = v;
    __syncthreads();
    for (int off = 1; off < 256; off <<= 1) {
        int t = (tid >= off) ? s[tid - off] : 0;
        __syncthreads();
        s[tid] += t;
        __syncthreads();
    }
    if (tid < nb) bsum[tid] = s[tid] - v;
}

__global__ __launch_bounds__(256) void k_scan3(int* __restrict__ row_ptr, int* __restrict__ cursor,
                                               const int* __restrict__ bsum, int n, int E) {
    int i = blockIdx.x * 256 + threadIdx.x;
    if (i < n) {
        int v = row_ptr[i] + bsum[i >> 9];
        row_ptr[i] = v;
        cursor[i] = v;
    }
    if (i == 0) row_ptr[n] = E;
}

__global__ __launch_bounds__(256) void k_scatter(const int* __restrict__ ei,
                                                 const float* __restrict__ ew, int E, int N,
                                                 int* __restrict__ cursor,
                                                 int2* __restrict__ cw) {
    int e = blockIdx.x * 256 + threadIdx.x;
    if (e < E) {
        unsigned r = (unsigned)ei[e];
        unsigned c = (unsigned)ei[E + e];
        if (r < (unsigned)N && c < (unsigned)N) {
            int p = atomicAdd(&cursor[r], 1);
            if ((unsigned)p < (unsigned)E) cw[p] = make_int2((int)c, __float_as_int(ew[e]));
        }
    }
}

// ---------------- weight prep: W[K][N] f32 -> WT[N][K] bf16 ----------------
__global__ __launch_bounds__(256) void k_prep_bt(const float* __restrict__ W1,
                                                 const float* __restrict__ W2,
                                                 unsigned short* __restrict__ W1T,
                                                 unsigned short* __restrict__ W2T) {
    int i = blockIdx.x * 256 + threadIdx.x;
    if (i < H1 * F_IN) {                       // W1T[n][k], n<128, k<256
        int n = i >> 8, k = i & 255;
        W1T[i] = f2bf(W1[k * H1 + n]);
    } else if (i < H1 * F_IN + H2 * H1) {      // W2T[n][k], n<64, k<128
        int j = i - H1 * F_IN;
        int n = j >> 7, k = j & 127;
        W2T[j] = f2bf(W2[k * H2 + n]);
    }
}

// ---------------- MFMA GEMM: C[M][NB](bf16) = A[M][K] @ BT[NB][K]^T ----------------
// Block: 256 thr = 4 waves (2x2), block tile 128 x NB, K-chunk 64.
// LDS tiles [row][64] bf16 with 16B-granule XOR swizzle: gran' = gran ^ (row&7).
// A/B fragments use the SAME (lane,elem)->k map, so the k-permutation cancels.

template <int K, bool ABF, int NB>
__global__ __launch_bounds__(256) void k_gemm_mfma(const void* __restrict__ A_,
                                                   const unsigned short* __restrict__ BT,
                                                   unsigned short* __restrict__ C, int M) {
    constexpr int NFR = NB / 32;               // n-frags per wave
    __shared__ unsigned short lA[128 * 64];
    __shared__ unsigned short lB[NB * 64];
    const int t = threadIdx.x;
    const int lane = t & 63, wid = t >> 6;
    const int wm = wid >> 1, wn = wid & 1;
    const long row0 = (long)blockIdx.x * 128;

    f32x4 acc[4][NFR];
#pragma unroll
    for (int mi = 0; mi < 4; ++mi)
#pragma unroll
        for (int ni = 0; ni < NFR; ++ni) acc[mi][ni] = (f32x4){0.f, 0.f, 0.f, 0.f};

    for (int kc = 0; kc < K; kc += 64) {
        // stage A tile: 128 rows x 64 k (quads of 4 bf16)
#pragma unroll
        for (int it = 0; it < 8; ++it) {
            int idx = t + it * 256;
            int r = idx >> 4, q = idx & 15;
            long gr = row0 + r;
            ushort4 uv;
            if (gr < M) {
                if constexpr (ABF) {
                    uv = *(const ushort4*)&((const unsigned short*)A_)[gr * K + kc + q * 4];
                } else {
                    float4 f = *(const float4*)&((const float*)A_)[gr * K + kc + q * 4];
                    uv.x = f2bf(f.x); uv.y = f2bf(f.y); uv.z = f2bf(f.z); uv.w = f2bf(f.w);
                }
            } else {
                uv.x = uv.y = uv.z = uv.w = 0;
            }
            int off = r * 64 + (((q >> 1) ^ (r & 7)) * 8) + (q & 1) * 4;
            *(ushort4*)&lA[off] = uv;
        }
        // stage B tile: NB rows x 64 k from BT (already bf16)
#pragma unroll
        for (int it = 0; it < NB / 16; ++it) {
            int idx = t + it * 256;
            int nr = idx >> 4, q = idx & 15;
            ushort4 uv = *(const ushort4*)&BT[(long)nr * K + kc + q * 4];
            int off = nr * 64 + (((q >> 1) ^ (nr & 7)) * 8) + (q & 1) * 4;
            *(ushort4*)&lB[off] = uv;
        }
        __syncthreads();
#pragma unroll
        for (int kk = 0; kk < 2; ++kk) {
            bf16x8 a[4], b[NFR];
#pragma unroll
            for (int mi = 0; mi < 4; ++mi) {
                int row = wm * 64 + mi * 16 + (lane & 15);
                int g = kk * 4 + (lane >> 4);
                a[mi] = *(const bf16x8*)&lA[row * 64 + ((g ^ (row & 7)) * 8)];
            }
#pragma unroll
            for (int ni = 0; ni < NFR; ++ni) {
                int nr = wn * (NB / 2) + ni * 16 + (lane & 15);
                int g = kk * 4 + (lane >> 4);
                b[ni] = *(const bf16x8*)&lB[nr * 64 + ((g ^ (nr & 7)) * 8)];
            }
#pragma unroll
            for (int mi = 0; mi < 4; ++mi)
#pragma unroll
                for (int ni = 0; ni < NFR; ++ni)
                    acc[mi][ni] = __builtin_amdgcn_mfma_f32_16x16x32_bf16(a[mi], b[ni],
                                                                          acc[mi][ni], 0, 0, 0);
        }
        __syncthreads();
    }
    // store C (bf16): row = 4*(lane>>4)+j, col = lane&15 within each 16x16 frag (m89-verified)
#pragma unroll
    for (int mi = 0; mi < 4; ++mi) {
#pragma unroll
        for (int ni = 0; ni < NFR; ++ni) {
#pragma unroll
            for (int j = 0; j < 4; ++j) {
                long gr = row0 + wm * 64 + mi * 16 + (lane >> 4) * 4 + j;
                int gc = wn * (NB / 2) + ni * 16 + (lane & 15);
                if (gr < M) C[gr * NB + gc] = f2bf(acc[mi][ni][j]);
            }
        }
    }
}

// ---------------- CSR SPMM layer1: h = relu(A*sup + b1), bf16 in/out ----------------
// one wave per row; lane handles cols {2*lane, 2*lane+1}; unroll-4 for MLP
__global__ __launch_bounds__(256) void k_spmm1(const int* __restrict__ row_ptr,
                                               const int2* __restrict__ cw,
                                               const unsigned short* __restrict__ sup,
                                               const float* __restrict__ bias,
                                               unsigned int* __restrict__ h, int n) {
    int wid = (blockIdx.x * 256 + threadIdx.x) >> 6;
    int lane = threadIdx.x & 63;
    if (wid >= n) return;
    int s = row_ptr[wid], e = row_ptr[wid + 1];
    float a0 = 0.f, a1 = 0.f;
    int i = s;
    for (; i + 4 <= e; i += 4) {
        int2 e0 = cw[i], e1 = cw[i + 1], e2 = cw[i + 2], e3 = cw[i + 3];
        unsigned u0 = *(const unsigned*)&sup[(long)e0.x * H1 + lane * 2];
        unsigned u1 = *(const unsigned*)&sup[(long)e1.x * H1 + lane * 2];
        unsigned u2 = *(const unsigned*)&sup[(long)e2.x * H1 + lane * 2];
        unsigned u3 = *(const unsigned*)&sup[(long)e3.x * H1 + lane * 2];
        float w0 = __int_as_float(e0.y), w1 = __int_as_float(e1.y);
        float w2 = __int_as_float(e2.y), w3 = __int_as_float(e3.y);
        a0 += w0 * bf2f((unsigned short)u0);
        a1 += w0 * bf2f((unsigned short)(u0 >> 16));
        a0 += w1 * bf2f((unsigned short)u1);
        a1 += w1 * bf2f((unsigned short)(u1 >> 16));
        a0 += w2 * bf2f((unsigned short)u2);
        a1 += w2 * bf2f((unsigned short)(u2 >> 16));
        a0 += w3 * bf2f((unsigned short)u3);
        a1 += w3 * bf2f((unsigned short)(u3 >> 16));
    }
    for (; i < e; ++i) {
        int2 ee = cw[i];
        unsigned u = *(const unsigned*)&sup[(long)ee.x * H1 + lane * 2];
        float w = __int_as_float(ee.y);
        a0 += w * bf2f((unsigned short)u);
        a1 += w * bf2f((unsigned short)(u >> 16));
    }
    float2 b = *(const float2*)&bias[lane * 2];
    float o0 = fmaxf(a0 + b.x, 0.f), o1 = fmaxf(a1 + b.y, 0.f);
    h[(long)wid * 64 + lane] = (unsigned)f2bf(o0) | ((unsigned)f2bf(o1) << 16);
}

// ---------------- CSR SPMM layer2: out = A*sup2 + b2, bf16 in, f32 out ----------------
__global__ __launch_bounds__(256) void k_spmm2(const int* __restrict__ row_ptr,
                                               const int2* __restrict__ cw,
                                               const unsigned short* __restrict__ sup2,
                                               const float* __restrict__ bias,
                                               float* __restrict__ out, int n) {
    int wid = (blockIdx.x * 256 + threadIdx.x) >> 6;
    int lane = threadIdx.x & 63;
    if (wid >= n) return;
    int s = row_ptr[wid], e = row_ptr[wid + 1];
    float a0 = 0.f;
    int i = s;
    for (; i + 4 <= e; i += 4) {
        int2 e0 = cw[i], e1 = cw[i + 1], e2 = cw[i + 2], e3 = cw[i + 3];
        unsigned short u0 = sup2[(long)e0.x * H2 + lane];
        unsigned short u1 = sup2[(long)e1.x * H2 + lane];
        unsigned short u2 = sup2[(long)e2.x * H2 + lane];
        unsigned short u3 = sup2[(long)e3.x * H2 + lane];
        a0 += __int_as_float(e0.y) * bf2f(u0);
        a0 += __int_as_float(e1.y) * bf2f(u1);
        a0 += __int_as_float(e2.y) * bf2f(u2);
        a0 += __int_as_float(e3.y) * bf2f(u3);
    }
    for (; i < e; ++i) {
        int2 ee = cw[i];
        a0 += __int_as_float(ee.y) * bf2f(sup2[(long)ee.x * H2 + lane]);
    }
    out[(long)wid * H2 + lane] = a0 + bias[lane];
}

// ---------------- launch ----------------

extern "C" void kernel_launch(void* const* d_in, const int* in_sizes, int n_in,
                              void* d_out, int out_size, void* d_ws, size_t ws_size,
                              hipStream_t stream) {
    (void)n_in; (void)out_size; (void)ws_size;
    const float* x = (const float*)d_in[0];
    const int* ei = (const int*)d_in[1];      // int32 (harness converts integer inputs)
    const float* ew = (const float*)d_in[2];
    const float* W1 = (const float*)d_in[3];
    const float* b1 = (const float*)d_in[4];
    const float* W2 = (const float*)d_in[5];
    const float* b2 = (const float*)d_in[6];
    float* out = (float*)d_out;

    const int E = in_sizes[2];
    const int N = in_sizes[0] / F_IN;  // 100000

    const int gE = (E + 255) / 256;
    const int nb = (N + 511) / 512;

    // workspace layout (256B-aligned), ~65MB total (R4 confirmed ws >= 116MB)
    size_t off = 0;
    auto take = [&off](size_t bytes) { size_t p = off; off = (off + bytes + 255) & ~(size_t)255; return p; };
    size_t o_sup    = take((size_t)N * H1 * 2);     // support1 bf16; reused as support2 bf16
    size_t o_h      = take((size_t)N * H1 * 2);     // h bf16 (packed pairs)
    size_t o_w1t    = take((size_t)H1 * F_IN * 2);  // W1T bf16 [128][256]
    size_t o_w2t    = take((size_t)H2 * H1 * 2);    // W2T bf16 [64][128]
    size_t o_rowptr = take(((size_t)N + 1) * 4);
    size_t o_cursor = take((size_t)N * 4);
    size_t o_bsum   = take(1024 * 4);
    size_t o_cw     = take((size_t)E * 8);          // packed (col, w)

    char* wsb = (char*)d_ws;
    unsigned short* sup  = (unsigned short*)(wsb + o_sup);
    unsigned int*   h    = (unsigned int*)(wsb + o_h);
    unsigned short* W1T  = (unsigned short*)(wsb + o_w1t);
    unsigned short* W2T  = (unsigned short*)(wsb + o_w2t);
    int* row_ptr = (int*)(wsb + o_rowptr);
    int* cursor  = (int*)(wsb + o_cursor);
    int* bsum    = (int*)(wsb + o_bsum);
    int2* cw     = (int2*)(wsb + o_cw);

    // CSR build
    k_zero32<<<(N + 255) / 256, 256, 0, stream>>>((unsigned int*)cursor, N);
    k_hist<<<gE, 256, 0, stream>>>(ei, E, N, cursor);
    k_scan1<<<nb, 512, 0, stream>>>(cursor, N, row_ptr, bsum);
    k_scan2<<<1, 256, 0, stream>>>(bsum, nb);
    k_scan3<<<(N + 255) / 256, 256, 0, stream>>>(row_ptr, cursor, bsum, N, E);
    k_scatter<<<gE, 256, 0, stream>>>(ei, ew, E, N, cursor, cw);

    // weights -> bf16 transposed
    k_prep_bt<<<(H1 * F_IN + H2 * H1 + 255) / 256, 256, 0, stream>>>(W1, W2, W1T, W2T);

    const int gM = (N + 127) / 128;
    // layer 1: support1 = x @ W1 (bf16) ; h = relu(spmm + b1) (bf16)
    k_gemm_mfma<F_IN, false, H1><<<gM, 256, 0, stream>>>(x, W1T, sup, N);
    k_spmm1<<<(N + 3) / 4, 256, 0, stream>>>(row_ptr, cw, sup, b1, h, N);
    // layer 2: support2 = h @ W2 (bf16, reuses sup buffer) ; out = spmm + b2 (f32)
    k_gemm_mfma<H1, true, H2><<<gM, 256, 0, stream>>>(h, W2T, sup, N);
    k_spmm2<<<(N + 3) / 4, 256, 0, stream>>>(row_ptr, cw, sup, b2, out, N);
}